// Round 7
// baseline (154.450 us; speedup 1.0000x reference)
//
#include <hip/hip_runtime.h>
#include <math.h>

#define NBATCH 8
#define NL 128
#define IND 512
#define DEPN 45
#define DEPD 16
#define WCOLS 528          // IN_DIM + DEP_DIM
#define NP 1664            // extended GEMM width
#define C_P1 0
#define C_P2 512
#define C_HT 1024
#define C_D1 1536
#define C_D2 1581
#define C_PAD 1626
#define BK 64

// ================= k_prep =================
// blocks [0,45):    Y1,Y2 (45x512), Ew[t]
// blocks [45,237):  transpose W1h/W2h/Wg -> Wt[d][m*512+o]
// blocks [237,301): hpa[row][d] = h[row][d] * wpos(row)
// blocks [301,365): zero Wt pad cols (8 d-rows each); blk 0 also fills bias_ext
__global__ __launch_bounds__(256) void k_prep(
    const float* __restrict__ h, const unsigned char* __restrict__ mask,
    const float* __restrict__ emb,
    const float* __restrict__ W1, const float* __restrict__ W2,
    const float* __restrict__ Wg,
    const float* __restrict__ b1, const float* __restrict__ b2,
    const float* __restrict__ bg,
    float* __restrict__ hpa, float* __restrict__ Wt,
    float* __restrict__ Y1, float* __restrict__ Y2, float* __restrict__ Ew,
    float* __restrict__ bias_ext) {
    int bid = blockIdx.x;
    int tid = threadIdx.x;

    if (bid < DEPN) {
        int t = bid;
        __shared__ float es[DEPD];
        __shared__ float red[4];
        if (tid < DEPD) es[tid] = emb[t * DEPD + tid];
        __syncthreads();
        float p = 0.f;
        for (int half = 0; half < 2; half++) {
            int o = tid + half * 256;
            float y1 = 0.f, y2 = 0.f;
#pragma unroll
            for (int e = 0; e < DEPD; e++) {
                y1 += es[e] * W1[o * WCOLS + IND + e];
                y2 += es[e] * W2[o * WCOLS + IND + e];
            }
            Y1[t * 512 + o] = y1;
            Y2[t * 512 + o] = y2;
            p += y1 * y2;
        }
        for (int off = 32; off; off >>= 1) p += __shfl_down(p, off, 64);
        if ((tid & 63) == 0) red[tid >> 6] = p;
        __syncthreads();
        if (tid == 0) Ew[t] = red[0] + red[1] + red[2] + red[3];
    } else if (bid < DEPN + 192) {
        int tile = bid - DEPN;
        int m = tile >> 6;
        int t = tile & 63;
        int orow = (t >> 3) * 64;
        int dcol = (t & 7) * 64;
        const float* W = (m == 0) ? W1 : (m == 1) ? W2 : Wg;
        int stride = (m == 2) ? IND : WCOLS;
        __shared__ float tl[64][65];
        int tx = tid & 63, ty = tid >> 6;
#pragma unroll
        for (int r = 0; r < 64; r += 4)
            tl[ty + r][tx] = W[(size_t)(orow + ty + r) * stride + dcol + tx];
        __syncthreads();
#pragma unroll
        for (int r = 0; r < 64; r += 4)
            Wt[(size_t)(dcol + ty + r) * NP + m * 512 + orow + tx] = tl[tx][ty + r];
    } else if (bid < DEPN + 192 + 64) {
        int blk = bid - (DEPN + 192);
        int rb = blk * 16;
        int b = rb >> 7;
        __shared__ int sflag, smin, smax;
        __shared__ float w16[16];
        if (tid == 0) { sflag = 0; smin = NL; smax = -1; }
        __syncthreads();
        const int* mi = (const int*)mask;
        if (tid < 128) {
            int v0 = mi[tid], v1 = mi[tid + 128];
            if ((unsigned)v0 > 1u || (unsigned)v1 > 1u) atomicOr(&sflag, 1);
        }
        __syncthreads();
        if (tid < 128) {
            int mval = sflag ? (int)mask[b * NL + tid] : mi[b * NL + tid];
            if (mval) { atomicMin(&smin, tid); atomicMax(&smax, tid); }
        }
        __syncthreads();
        if (tid < 16) {
            int any = (smax >= 0);
            int s = any ? smin : 0;
            int e = any ? smax : (NL - 1);
            int i = (rb & 127) + tid;
            const float invL = 1.0f / (float)NL;
            float w;
            if (i < s)      w = 1.0f - (float)(s - i) * invL;
            else if (i > e) w = 1.0f - (float)(i - e) * invL;
            else            w = 0.0f;
            int mval = sflag ? (int)mask[b * NL + i] : mi[b * NL + i];
            if (mval) w = 0.0f;
            w16[tid] = w;
        }
        __syncthreads();
        for (int idx = tid; idx < 16 * 128; idx += 256) {
            int r = idx >> 7, dc = (idx & 127) << 2;
            float4 hv = *(const float4*)&h[(size_t)(rb + r) * IND + dc];
            float wv = w16[r];
            hv.x *= wv; hv.y *= wv; hv.z *= wv; hv.w *= wv;
            *(float4*)&hpa[(size_t)(rb + r) * IND + dc] = hv;
        }
    } else {
        // ---- zero pad cols of Wt (8 d-rows per block); blk 0: bias_ext base ----
        int blk = bid - (DEPN + 192 + 64);   // 0..63
        int d0 = blk * 8;
        int r = tid >> 5, c = tid & 31;
        Wt[(size_t)(d0 + r) * NP + C_PAD + c] = 0.f;
        if (c < 6) Wt[(size_t)(d0 + r) * NP + C_PAD + 32 + c] = 0.f;
        if (blk == 0) {
            for (int i = tid; i < 512; i += 256) {
                bias_ext[C_P1 + i] = b1[i];
                bias_ext[C_P2 + i] = b2[i];
                bias_ext[C_HT + i] = bg[i];
            }
            if (tid < NP - C_PAD) bias_ext[C_PAD + tid] = 0.f;
        }
    }
}

// ================= k_prep2: Z columns + D-bias =================
__global__ __launch_bounds__(256) void k_prep2(
    const float* __restrict__ b1, const float* __restrict__ b2,
    const float* __restrict__ Y1, const float* __restrict__ Y2,
    const float* __restrict__ Ew,
    float* __restrict__ Wt, float* __restrict__ bias_ext) {
    int t = blockIdx.x;
    int m = blockIdx.y;
    int chunk = blockIdx.z;
    int tid = threadIdx.x;
    int w = tid >> 6, l = tid & 63;
    __shared__ float ys[512];
    const float* Y = (m == 0) ? Y2 : Y1;
    ys[tid] = Y[t * 512 + tid];
    ys[tid + 256] = Y[t * 512 + tid + 256];
    __syncthreads();

    int dbase = chunk * 128;
    int colD = (m == 0) ? (C_D1 + t) : (C_D2 + t);
    for (int r = w; r < 128; r += 4) {
        int d = dbase + r;
        const float* wr = Wt + (size_t)d * NP + m * 512;
        float s = 0.f;
#pragma unroll
        for (int k = 0; k < 8; k++) s += wr[l + k * 64] * ys[l + k * 64];
        for (int off = 32; off; off >>= 1) s += __shfl_down(s, off, 64);
        if (l == 0) Wt[(size_t)d * NP + colD] = s;
    }

    if (chunk == 0 && tid < 64) {
        const float* bb = (m == 0) ? b1 : b2;
        float s = 0.f;
#pragma unroll
        for (int k = 0; k < 8; k++) s += bb[tid + k * 64] * ys[tid + k * 64];
        for (int off = 32; off; off >>= 1) s += __shfl_down(s, off, 64);
        if (tid == 0) {
            if (m == 0) bias_ext[C_D1 + t] = s + Ew[t];
            else        bias_ext[C_D2 + t] = s;
        }
    }
}

// ================= k3: Pout = hpa @ Wt + bias_ext =================
// Block 16 rows x 128 cols, 128 threads = 32 col x 4 rowgroups, thread
// tile 4r x 4c.  W panel staged in LDS per BK=64 K-step so cross-rowgroup
// reuse is LDS broadcast, not redundant L2 reads.  Next-step loads issue
// right after ds_writes (T14 issue-early) to hide L2 latency under compute.
// LDS 36 KB -> 4 blocks/CU (8 waves/CU).
#define ACCR(A, H, W0, W1_, W2_, W3_) \
    A.x += H.x*W0.x + H.y*W1_.x + H.z*W2_.x + H.w*W3_.x; \
    A.y += H.x*W0.y + H.y*W1_.y + H.z*W2_.y + H.w*W3_.y; \
    A.z += H.x*W0.z + H.y*W1_.z + H.z*W2_.z + H.w*W3_.z; \
    A.w += H.x*W0.w + H.y*W1_.w + H.z*W2_.w + H.w*W3_.w;

__global__ __launch_bounds__(128) void k3_gemm(
    const float* __restrict__ hpa, const float* __restrict__ Wt,
    const float* __restrict__ bias_ext, float* __restrict__ Pout) {
    int bid = blockIdx.x;              // 832 = 64 rowblocks x 13 colchunks
    int rb = (bid & 63) << 4;
    int cb = (bid >> 6) << 7;
    int tid = threadIdx.x;
    int c = tid & 31, g = tid >> 5;
    int col = cb + (c << 2);
    int g4 = g << 2;

    __shared__ float Wl[BK * 128];     // 32 KB  [d][col] row-major
    __shared__ float hl[16 * BK];      // 4 KB   [r][d] row-major

    const float* Wbase = Wt + cb;
    const float* hbase = hpa + (size_t)rb * IND;

    float4 wst[16];
    float4 hst[2];
    // prologue: load step 0
#pragma unroll
    for (int k = 0; k < 16; k++) {
        int f = k * 128 + tid;
        wst[k] = *(const float4*)(Wbase + (size_t)(f >> 5) * NP + ((f & 31) << 2));
    }
#pragma unroll
    for (int k = 0; k < 2; k++) {
        int f = k * 128 + tid;
        hst[k] = *(const float4*)(hbase + (size_t)(f >> 4) * IND + ((f & 15) << 2));
    }

    float4 z = {0.f, 0.f, 0.f, 0.f};
    float4 acc0 = z, acc1 = z, acc2 = z, acc3 = z;

    for (int s = 0; s < 8; s++) {
        if (s) __syncthreads();        // all waves done reading previous tile
#pragma unroll
        for (int k = 0; k < 16; k++)
            *(float4*)&Wl[(k * 128 + tid) << 2] = wst[k];
#pragma unroll
        for (int k = 0; k < 2; k++)
            *(float4*)&hl[(k * 128 + tid) << 2] = hst[k];
        if (s < 7) {                   // issue next-step loads (hide under compute)
            int d0n = (s + 1) * BK;
#pragma unroll
            for (int k = 0; k < 16; k++) {
                int f = k * 128 + tid;
                wst[k] = *(const float4*)(Wbase + (size_t)(d0n + (f >> 5)) * NP + ((f & 31) << 2));
            }
#pragma unroll
            for (int k = 0; k < 2; k++) {
                int f = k * 128 + tid;
                hst[k] = *(const float4*)(hbase + (size_t)(f >> 4) * IND + d0n + ((f & 15) << 2));
            }
        }
        __syncthreads();               // tile visible
#pragma unroll
        for (int dd = 0; dd < BK; dd += 4) {
            float4 w0 = *(const float4*)&Wl[(dd + 0) * 128 + (c << 2)];
            float4 w1 = *(const float4*)&Wl[(dd + 1) * 128 + (c << 2)];
            float4 w2 = *(const float4*)&Wl[(dd + 2) * 128 + (c << 2)];
            float4 w3 = *(const float4*)&Wl[(dd + 3) * 128 + (c << 2)];
            float4 h0 = *(const float4*)&hl[(g4 + 0) * BK + dd];
            float4 h1 = *(const float4*)&hl[(g4 + 1) * BK + dd];
            float4 h2 = *(const float4*)&hl[(g4 + 2) * BK + dd];
            float4 h3 = *(const float4*)&hl[(g4 + 3) * BK + dd];
            ACCR(acc0, h0, w0, w1, w2, w3)
            ACCR(acc1, h1, w0, w1, w2, w3)
            ACCR(acc2, h2, w0, w1, w2, w3)
            ACCR(acc3, h3, w0, w1, w2, w3)
        }
    }

    float4 bv = *(const float4*)(bias_ext + col);
    float4 o0, o1, o2, o3;
    o0.x = acc0.x + bv.x; o0.y = acc0.y + bv.y; o0.z = acc0.z + bv.z; o0.w = acc0.w + bv.w;
    o1.x = acc1.x + bv.x; o1.y = acc1.y + bv.y; o1.z = acc1.z + bv.z; o1.w = acc1.w + bv.w;
    o2.x = acc2.x + bv.x; o2.y = acc2.y + bv.y; o2.z = acc2.z + bv.z; o2.w = acc2.w + bv.w;
    o3.x = acc3.x + bv.x; o3.y = acc3.y + bv.y; o3.z = acc3.z + bv.z; o3.w = acc3.w + bv.w;
    *(float4*)&Pout[(size_t)(rb + g4 + 0) * NP + col] = o0;
    *(float4*)&Pout[(size_t)(rb + g4 + 1) * NP + col] = o1;
    *(float4*)&Pout[(size_t)(rb + g4 + 2) * NP + col] = o2;
    *(float4*)&Pout[(size_t)(rb + g4 + 3) * NP + col] = o3;
}

// ================= k5: scores lookup + normalize + A@HT + relu =================
__global__ __launch_bounds__(128) void k5_out(
    const float* __restrict__ P, const int* __restrict__ dep,
    const float* __restrict__ bias, float* __restrict__ out) {
    int row = blockIdx.x;        // 1024
    int b = row >> 7;
    int tid = threadIdx.x;       // 128
    __shared__ float comb[DEPN];
    __shared__ float a[NL];
    __shared__ float red[2];
    __shared__ float sumv;

    const float* Prow = P + (size_t)row * NP;
    // c0 = P1 . P2
    float4 p1 = *(const float4*)(Prow + C_P1 + tid * 4);
    float4 p2 = *(const float4*)(Prow + C_P2 + tid * 4);
    float lc = p1.x * p2.x + p1.y * p2.y + p1.z * p2.z + p1.w * p2.w;
    for (int off = 32; off; off >>= 1) lc += __shfl_down(lc, off, 64);
    if ((tid & 63) == 0) red[tid >> 6] = lc;
    if (tid < DEPN) comb[tid] = Prow[C_D1 + tid] + Prow[C_D2 + tid];
    __syncthreads();

    float c0 = red[0] + red[1];
    int tt = dep[(size_t)row * NL + tid];
    float sc = (tt != 0) ? expf(c0 + comb[tt]) : 0.f;
    a[tid] = sc;
    __syncthreads();
    if (tid < 64) {
        float v = a[tid] + a[tid + 64];
        for (int off = 32; off; off >>= 1) v += __shfl_down(v, off, 64);
        if (tid == 0) sumv = v;
    }
    __syncthreads();
    float inv = 1.0f / (sumv + 1e-6f);

    // out = relu(inv * sum_j a[j]*HT[b,j,:] + bias)
    const float* htb = P + (size_t)b * NL * NP + C_HT + tid * 4;
    float sx = 0.f, sy = 0.f, sz = 0.f, sw = 0.f;
#pragma unroll 4
    for (int j = 0; j < NL; j += 2) {
        float a0 = a[j], a1 = a[j + 1];
        float4 v0 = *(const float4*)(htb + (size_t)j * NP);
        float4 v1 = *(const float4*)(htb + (size_t)(j + 1) * NP);
        sx += a0 * v0.x + a1 * v1.x;
        sy += a0 * v0.y + a1 * v1.y;
        sz += a0 * v0.z + a1 * v1.z;
        sw += a0 * v0.w + a1 * v1.w;
    }
    float4 bv = *(const float4*)&bias[tid * 4];
    float4 o;
    o.x = fmaxf(sx * inv + bv.x, 0.f);
    o.y = fmaxf(sy * inv + bv.y, 0.f);
    o.z = fmaxf(sz * inv + bv.z, 0.f);
    o.w = fmaxf(sw * inv + bv.w, 0.f);
    *(float4*)&out[(size_t)row * 512 + tid * 4] = o;
}

extern "C" void kernel_launch(void* const* d_in, const int* in_sizes, int n_in,
                              void* d_out, int out_size, void* d_ws, size_t ws_size,
                              hipStream_t stream) {
    const float* h    = (const float*)d_in[0];
    const int* dep    = (const int*)d_in[1];
    const unsigned char* mask = (const unsigned char*)d_in[2];
    const float* emb  = (const float*)d_in[3];
    const float* W1   = (const float*)d_in[4];
    const float* b1   = (const float*)d_in[5];
    const float* W2   = (const float*)d_in[6];
    const float* b2   = (const float*)d_in[7];
    const float* Wg   = (const float*)d_in[8];
    const float* bg   = (const float*)d_in[9];
    const float* bias = (const float*)d_in[10];
    float* out = (float*)d_out;

    float* ws = (float*)d_ws;
    float* hpa      = ws;                      // 524288
    float* Wt       = hpa + 524288;            // 512*1664 = 851968
    float* bias_ext = Wt + 851968;             // 1664
    float* Y1       = bias_ext + 1664;         // 23040
    float* Y2       = Y1 + 23040;              // 23040
    float* Ew       = Y2 + 23040;              // 64
    float* Pout     = Ew + 64;                 // 1024*1664 = 1703936

    k_prep<<<DEPN + 192 + 64 + 64, 256, 0, stream>>>(h, mask, emb, W1, W2, Wg,
                                                     b1, b2, bg,
                                                     hpa, Wt, Y1, Y2, Ew, bias_ext);
    dim3 g2(DEPN, 2, 4);
    k_prep2<<<g2, 256, 0, stream>>>(b1, b2, Y1, Y2, Ew, Wt, bias_ext);
    k3_gemm<<<832, 128, 0, stream>>>(hpa, Wt, bias_ext, Pout);
    k5_out<<<NBATCH * NL, 128, 0, stream>>>(Pout, dep, bias, out);
}

// Round 8
// 78.185 us; speedup vs baseline: 1.9754x; 1.9754x over previous
//
#include <hip/hip_runtime.h>
#include <hip/hip_bf16.h>
#include <math.h>

#define NBATCH 8
#define NL 128
#define IND 512
#define DEPN 45
#define DEPD 16
#define WCOLS 528          // IN_DIM + DEP_DIM
#define NP 1664            // extended width (P1|P2|HT|D1|D2|pad)
#define C_P1 0
#define C_P2 512
#define C_HT 1024
#define C_D1 1536
#define C_D2 1581
#define C_PAD 1626

typedef __attribute__((ext_vector_type(8))) short bf16x8;
typedef __attribute__((ext_vector_type(4))) float f32x4;

__device__ inline ushort f2bf(float x) {
    __hip_bfloat16 b = __float2bfloat16(x);
    return *reinterpret_cast<ushort*>(&b);
}
__device__ inline float bf2f(ushort u) {
    __hip_bfloat16 b;
    *reinterpret_cast<ushort*>(&b) = u;
    return __bfloat162float(b);
}

// ================= k_prep =================
// blocks [0,45):     Y1,Y2 (45x512), Ew[t]
// blocks [45,109):   A_hi/A_lo = bf16-split of h*wpos  (64 blocks x 16 rows)
// blocks [109,205):  B_hi/B_lo rows 0..1535 = bf16-split of W1h|W2h|Wg (96 x 16)
// blocks [205,213):  zero B rows 1536..1663 (prep2 overwrites 1536..1625);
//                    blk 205 also fills bias_ext base/pad
__global__ __launch_bounds__(256) void k_prep(
    const float* __restrict__ h, const unsigned char* __restrict__ mask,
    const float* __restrict__ emb,
    const float* __restrict__ W1, const float* __restrict__ W2,
    const float* __restrict__ Wg,
    const float* __restrict__ b1, const float* __restrict__ b2,
    const float* __restrict__ bg,
    ushort* __restrict__ A_hi, ushort* __restrict__ A_lo,
    ushort* __restrict__ B_hi, ushort* __restrict__ B_lo,
    float* __restrict__ Y1, float* __restrict__ Y2, float* __restrict__ Ew,
    float* __restrict__ bias_ext) {
    int bid = blockIdx.x;
    int tid = threadIdx.x;

    if (bid < DEPN) {
        int t = bid;
        __shared__ float es[DEPD];
        __shared__ float red[4];
        if (tid < DEPD) es[tid] = emb[t * DEPD + tid];
        __syncthreads();
        float p = 0.f;
        for (int half = 0; half < 2; half++) {
            int o = tid + half * 256;
            float y1 = 0.f, y2 = 0.f;
#pragma unroll
            for (int e = 0; e < DEPD; e++) {
                y1 += es[e] * W1[o * WCOLS + IND + e];
                y2 += es[e] * W2[o * WCOLS + IND + e];
            }
            Y1[t * 512 + o] = y1;
            Y2[t * 512 + o] = y2;
            p += y1 * y2;
        }
        for (int off = 32; off; off >>= 1) p += __shfl_down(p, off, 64);
        if ((tid & 63) == 0) red[tid >> 6] = p;
        __syncthreads();
        if (tid == 0) Ew[t] = red[0] + red[1] + red[2] + red[3];
    } else if (bid < 109) {
        // ---- A conversion: 16 rows, with position-aware weight ----
        int blk = bid - 45;
        int rb = blk * 16;
        int b = rb >> 7;
        __shared__ int sflag, smin, smax;
        __shared__ float w16[16];
        if (tid == 0) { sflag = 0; smin = NL; smax = -1; }
        __syncthreads();
        const int* mi = (const int*)mask;
        if (tid < 128) {
            int v0 = mi[tid], v1 = mi[tid + 128];
            if ((unsigned)v0 > 1u || (unsigned)v1 > 1u) atomicOr(&sflag, 1);
        }
        __syncthreads();
        if (tid < 128) {
            int mval = sflag ? (int)mask[b * NL + tid] : mi[b * NL + tid];
            if (mval) { atomicMin(&smin, tid); atomicMax(&smax, tid); }
        }
        __syncthreads();
        if (tid < 16) {
            int any = (smax >= 0);
            int s = any ? smin : 0;
            int e = any ? smax : (NL - 1);
            int i = (rb & 127) + tid;
            const float invL = 1.0f / (float)NL;
            float w;
            if (i < s)      w = 1.0f - (float)(s - i) * invL;
            else if (i > e) w = 1.0f - (float)(i - e) * invL;
            else            w = 0.0f;
            int mval = sflag ? (int)mask[b * NL + i] : mi[b * NL + i];
            if (mval) w = 0.0f;
            w16[tid] = w;
        }
        __syncthreads();
        for (int idx = tid; idx < 16 * 128; idx += 256) {
            int r = idx >> 7, dc = (idx & 127) << 2;
            float4 hv = *(const float4*)&h[(size_t)(rb + r) * IND + dc];
            float wv = w16[r];
            hv.x *= wv; hv.y *= wv; hv.z *= wv; hv.w *= wv;
            ushort4 hi4;
            hi4.x = f2bf(hv.x); hi4.y = f2bf(hv.y); hi4.z = f2bf(hv.z); hi4.w = f2bf(hv.w);
            ushort4 lo4;
            lo4.x = f2bf(hv.x - bf2f(hi4.x));
            lo4.y = f2bf(hv.y - bf2f(hi4.y));
            lo4.z = f2bf(hv.z - bf2f(hi4.z));
            lo4.w = f2bf(hv.w - bf2f(hi4.w));
            *(ushort4*)&A_hi[(size_t)(rb + r) * IND + dc] = hi4;
            *(ushort4*)&A_lo[(size_t)(rb + r) * IND + dc] = lo4;
        }
    } else if (bid < 205) {
        // ---- B conversion rows 0..1535 ----
        int blk = bid - 109;
        int nb = blk * 16;
        for (int idx = tid; idx < 16 * 128; idx += 256) {
            int r = idx >> 7, dc = (idx & 127) << 2;
            int n = nb + r;
            const float* src;
            if (n < 512)       src = W1 + (size_t)n * WCOLS + dc;
            else if (n < 1024) src = W2 + (size_t)(n - 512) * WCOLS + dc;
            else               src = Wg + (size_t)(n - 1024) * IND + dc;
            float4 wv = *(const float4*)src;
            ushort4 hi4;
            hi4.x = f2bf(wv.x); hi4.y = f2bf(wv.y); hi4.z = f2bf(wv.z); hi4.w = f2bf(wv.w);
            ushort4 lo4;
            lo4.x = f2bf(wv.x - bf2f(hi4.x));
            lo4.y = f2bf(wv.y - bf2f(hi4.y));
            lo4.z = f2bf(wv.z - bf2f(hi4.z));
            lo4.w = f2bf(wv.w - bf2f(hi4.w));
            *(ushort4*)&B_hi[(size_t)n * IND + dc] = hi4;
            *(ushort4*)&B_lo[(size_t)n * IND + dc] = lo4;
        }
    } else {
        // ---- zero B rows 1536..1663; blk 205: bias_ext base+pad ----
        int blk = bid - 205;             // 0..7
        int nb = 1536 + blk * 16;
        ushort4 z4 = {0, 0, 0, 0};
        for (int idx = tid; idx < 16 * 128; idx += 256) {
            int r = idx >> 7, dc = (idx & 127) << 2;
            int n = nb + r;
            *(ushort4*)&B_hi[(size_t)n * IND + dc] = z4;
            *(ushort4*)&B_lo[(size_t)n * IND + dc] = z4;
        }
        if (blk == 0) {
            for (int i = tid; i < 512; i += 256) {
                bias_ext[C_P1 + i] = b1[i];
                bias_ext[C_P2 + i] = b2[i];
                bias_ext[C_HT + i] = bg[i];
            }
            if (tid < NP - C_PAD) bias_ext[C_PAD + tid] = 0.f;
        }
    }
}

// ================= k_prep2: Z rows of B + D-bias =================
// grid (45 t, 2 m, 2 dhalf), 256 thr; thread owns d = dhalf*256+tid.
// m=0: B[C_D1+t][d] = bf16split( sum_o W1[o][d]*Y2[t][o] ), bias=b1.Y2+Ew
// m=1: B[C_D2+t][d] = bf16split( sum_o W2[o][d]*Y1[t][o] ), bias=b2.Y1
__global__ __launch_bounds__(256) void k_prep2(
    const float* __restrict__ W1, const float* __restrict__ W2,
    const float* __restrict__ b1, const float* __restrict__ b2,
    const float* __restrict__ Y1, const float* __restrict__ Y2,
    const float* __restrict__ Ew,
    ushort* __restrict__ B_hi, ushort* __restrict__ B_lo,
    float* __restrict__ bias_ext) {
    int t = blockIdx.x;
    int m = blockIdx.y;
    int dh = blockIdx.z;
    int tid = threadIdx.x;
    __shared__ float ys[512];
    const float* Y = (m == 0) ? Y2 : Y1;
    ys[tid] = Y[t * 512 + tid];
    ys[tid + 256] = Y[t * 512 + tid + 256];
    __syncthreads();

    const float* Wsrc = (m == 0) ? W1 : W2;
    int d = dh * 256 + tid;
    float s = 0.f;
#pragma unroll 8
    for (int o = 0; o < 512; o++)
        s += Wsrc[(size_t)o * WCOLS + d] * ys[o];

    int row = ((m == 0) ? C_D1 : C_D2) + t;
    ushort hi = f2bf(s);
    ushort lo = f2bf(s - bf2f(hi));
    B_hi[(size_t)row * IND + d] = hi;
    B_lo[(size_t)row * IND + d] = lo;

    if (dh == 0 && tid < 64) {
        const float* bb = (m == 0) ? b1 : b2;
        float sb = 0.f;
#pragma unroll
        for (int k = 0; k < 8; k++) sb += bb[tid + k * 64] * ys[tid + k * 64];
        for (int off = 32; off; off >>= 1) sb += __shfl_down(sb, off, 64);
        if (tid == 0) bias_ext[row] = sb + ((m == 0) ? Ew[t] : 0.f);
    }
}

// ================= k3: Pout = A @ B^T + bias_ext  (MFMA, hi/lo bf16) =================
// A[1024][512], B stored as [n=1664][k=512] (= B^T rows). Product via
// Ah.Bh + Ah.Bl + Al.Bh, fp32 accum.  256 thr = 4 waves; wave tile 32x32
// (2m x 2n frags of 16x16x32); block tile 64x64; grid (16, 26).
// Frag layout (m89/m92-verified): A/B lane l reads 8 contiguous k at
// row/col = l&15, kbase = (l>>4)*8;  D: col = l&15, row = (l>>4)*4 + reg.
#define LOADSET(P, KS) \
    P##a0h = *(const bf16x8*)(A_hi + (size_t)rA0 * IND + (KS) * 32 + kg8); \
    P##a0l = *(const bf16x8*)(A_lo + (size_t)rA0 * IND + (KS) * 32 + kg8); \
    P##a1h = *(const bf16x8*)(A_hi + (size_t)rA1 * IND + (KS) * 32 + kg8); \
    P##a1l = *(const bf16x8*)(A_lo + (size_t)rA1 * IND + (KS) * 32 + kg8); \
    P##b0h = *(const bf16x8*)(B_hi + (size_t)cB0 * IND + (KS) * 32 + kg8); \
    P##b0l = *(const bf16x8*)(B_lo + (size_t)cB0 * IND + (KS) * 32 + kg8); \
    P##b1h = *(const bf16x8*)(B_hi + (size_t)cB1 * IND + (KS) * 32 + kg8); \
    P##b1l = *(const bf16x8*)(B_lo + (size_t)cB1 * IND + (KS) * 32 + kg8);

#define MFMASET(P) \
    acc00 = __builtin_amdgcn_mfma_f32_16x16x32_bf16(P##a0h, P##b0h, acc00, 0, 0, 0); \
    acc00 = __builtin_amdgcn_mfma_f32_16x16x32_bf16(P##a0h, P##b0l, acc00, 0, 0, 0); \
    acc00 = __builtin_amdgcn_mfma_f32_16x16x32_bf16(P##a0l, P##b0h, acc00, 0, 0, 0); \
    acc01 = __builtin_amdgcn_mfma_f32_16x16x32_bf16(P##a0h, P##b1h, acc01, 0, 0, 0); \
    acc01 = __builtin_amdgcn_mfma_f32_16x16x32_bf16(P##a0h, P##b1l, acc01, 0, 0, 0); \
    acc01 = __builtin_amdgcn_mfma_f32_16x16x32_bf16(P##a0l, P##b1h, acc01, 0, 0, 0); \
    acc10 = __builtin_amdgcn_mfma_f32_16x16x32_bf16(P##a1h, P##b0h, acc10, 0, 0, 0); \
    acc10 = __builtin_amdgcn_mfma_f32_16x16x32_bf16(P##a1h, P##b0l, acc10, 0, 0, 0); \
    acc10 = __builtin_amdgcn_mfma_f32_16x16x32_bf16(P##a1l, P##b0h, acc10, 0, 0, 0); \
    acc11 = __builtin_amdgcn_mfma_f32_16x16x32_bf16(P##a1h, P##b1h, acc11, 0, 0, 0); \
    acc11 = __builtin_amdgcn_mfma_f32_16x16x32_bf16(P##a1h, P##b1l, acc11, 0, 0, 0); \
    acc11 = __builtin_amdgcn_mfma_f32_16x16x32_bf16(P##a1l, P##b1h, acc11, 0, 0, 0);

__global__ __launch_bounds__(256) void k3_gemm(
    const ushort* __restrict__ A_hi, const ushort* __restrict__ A_lo,
    const ushort* __restrict__ B_hi, const ushort* __restrict__ B_lo,
    const float* __restrict__ bias_ext, float* __restrict__ Pout) {
    int tid = threadIdx.x;
    int wid = tid >> 6, lane = tid & 63;
    int lrow = lane & 15, kg8 = (lane >> 4) << 3;
    int mbase = blockIdx.x * 64 + (wid >> 1) * 32;
    int nbase = blockIdx.y * 64 + (wid & 1) * 32;
    int rA0 = mbase + lrow, rA1 = rA0 + 16;
    int cB0 = nbase + lrow, cB1 = cB0 + 16;

    f32x4 acc00 = {0.f, 0.f, 0.f, 0.f};
    f32x4 acc01 = acc00, acc10 = acc00, acc11 = acc00;
    bf16x8 pa0h, pa0l, pa1h, pa1l, pb0h, pb0l, pb1h, pb1l;
    bf16x8 qa0h, qa0l, qa1h, qa1l, qb0h, qb0l, qb1h, qb1l;

    LOADSET(p, 0)
#pragma unroll
    for (int ks = 0; ks < 16; ks += 2) {
        LOADSET(q, ks + 1)
        MFMASET(p)
        int kn = (ks + 2) & 15;      // last iter: dummy reload of 0 (unused)
        LOADSET(p, kn)
        MFMASET(q)
    }

    int r0 = (lane >> 4) << 2;
    int col0 = nbase + lrow;
    int col1 = col0 + 16;
    float bv0 = bias_ext[col0];
    float bv1 = bias_ext[col1];
#pragma unroll
    for (int r = 0; r < 4; ++r) {
        int row0 = mbase + r0 + r;
        int row1 = row0 + 16;
        Pout[(size_t)row0 * NP + col0] = acc00[r] + bv0;
        Pout[(size_t)row0 * NP + col1] = acc01[r] + bv1;
        Pout[(size_t)row1 * NP + col0] = acc10[r] + bv0;
        Pout[(size_t)row1 * NP + col1] = acc11[r] + bv1;
    }
}

// ================= k5: scores lookup + normalize + A@HT + relu =================
__global__ __launch_bounds__(128) void k5_out(
    const float* __restrict__ P, const int* __restrict__ dep,
    const float* __restrict__ bias, float* __restrict__ out) {
    int row = blockIdx.x;        // 1024
    int b = row >> 7;
    int tid = threadIdx.x;       // 128
    __shared__ float comb[DEPN];
    __shared__ float a[NL];
    __shared__ float red[2];
    __shared__ float sumv;

    const float* Prow = P + (size_t)row * NP;
    float4 p1 = *(const float4*)(Prow + C_P1 + tid * 4);
    float4 p2 = *(const float4*)(Prow + C_P2 + tid * 4);
    float lc = p1.x * p2.x + p1.y * p2.y + p1.z * p2.z + p1.w * p2.w;
    for (int off = 32; off; off >>= 1) lc += __shfl_down(lc, off, 64);
    if ((tid & 63) == 0) red[tid >> 6] = lc;
    if (tid < DEPN) comb[tid] = Prow[C_D1 + tid] + Prow[C_D2 + tid];
    __syncthreads();

    float c0 = red[0] + red[1];
    int tt = dep[(size_t)row * NL + tid];
    float sc = (tt != 0) ? expf(c0 + comb[tt]) : 0.f;
    a[tid] = sc;
    __syncthreads();
    if (tid < 64) {
        float v = a[tid] + a[tid + 64];
        for (int off = 32; off; off >>= 1) v += __shfl_down(v, off, 64);
        if (tid == 0) sumv = v;
    }
    __syncthreads();
    float inv = 1.0f / (sumv + 1e-6f);

    const float* htb = P + (size_t)b * NL * NP + C_HT + tid * 4;
    float sx = 0.f, sy = 0.f, sz = 0.f, sw = 0.f;
#pragma unroll 4
    for (int j = 0; j < NL; j += 2) {
        float a0 = a[j], a1 = a[j + 1];
        float4 v0 = *(const float4*)(htb + (size_t)j * NP);
        float4 v1 = *(const float4*)(htb + (size_t)(j + 1) * NP);
        sx += a0 * v0.x + a1 * v1.x;
        sy += a0 * v0.y + a1 * v1.y;
        sz += a0 * v0.z + a1 * v1.z;
        sw += a0 * v0.w + a1 * v1.w;
    }
    float4 bv = *(const float4*)&bias[tid * 4];
    float4 o;
    o.x = fmaxf(sx * inv + bv.x, 0.f);
    o.y = fmaxf(sy * inv + bv.y, 0.f);
    o.z = fmaxf(sz * inv + bv.z, 0.f);
    o.w = fmaxf(sw * inv + bv.w, 0.f);
    *(float4*)&out[(size_t)row * 512 + tid * 4] = o;
}

extern "C" void kernel_launch(void* const* d_in, const int* in_sizes, int n_in,
                              void* d_out, int out_size, void* d_ws, size_t ws_size,
                              hipStream_t stream) {
    const float* h    = (const float*)d_in[0];
    const int* dep    = (const int*)d_in[1];
    const unsigned char* mask = (const unsigned char*)d_in[2];
    const float* emb  = (const float*)d_in[3];
    const float* W1   = (const float*)d_in[4];
    const float* b1   = (const float*)d_in[5];
    const float* W2   = (const float*)d_in[6];
    const float* b2   = (const float*)d_in[7];
    const float* Wg   = (const float*)d_in[8];
    const float* bg   = (const float*)d_in[9];
    const float* bias = (const float*)d_in[10];
    float* out = (float*)d_out;

    char* p = (char*)d_ws;
    ushort* A_hi = (ushort*)p;  p += (size_t)1024 * 512 * 2;   // 1 MB
    ushort* A_lo = (ushort*)p;  p += (size_t)1024 * 512 * 2;
    ushort* B_hi = (ushort*)p;  p += (size_t)1664 * 512 * 2;   // 1.7 MB
    ushort* B_lo = (ushort*)p;  p += (size_t)1664 * 512 * 2;
    float* bias_ext = (float*)p; p += 1664 * 4;
    float* Y1 = (float*)p;      p += 23040 * 4;
    float* Y2 = (float*)p;      p += 23040 * 4;
    float* Ew = (float*)p;      p += 64 * 4;
    float* Pout = (float*)p;    // 1024*1664*4 = 6.8 MB

    k_prep<<<213, 256, 0, stream>>>(h, mask, emb, W1, W2, Wg, b1, b2, bg,
                                    A_hi, A_lo, B_hi, B_lo, Y1, Y2, Ew, bias_ext);
    dim3 g2(DEPN, 2, 2);
    k_prep2<<<g2, 256, 0, stream>>>(W1, W2, b1, b2, Y1, Y2, Ew, B_hi, B_lo, bias_ext);
    dim3 g3(16, 26);
    k3_gemm<<<g3, 256, 0, stream>>>(A_hi, A_lo, B_hi, B_lo, bias_ext, Pout);
    k5_out<<<NBATCH * NL, 128, 0, stream>>>(Pout, dep, bias, out);
}

// Round 9
// 64.212 us; speedup vs baseline: 2.4053x; 1.2176x over previous
//
#include <hip/hip_runtime.h>
#include <hip/hip_bf16.h>
#include <math.h>

#define NBATCH 8
#define NL 128
#define IND 512
#define DEPN 45
#define DEPD 16
#define WCOLS 528          // IN_DIM + DEP_DIM
#define NP 1664            // extended width (P1|P2|HT|D1|D2|pad)
#define C_P1 0
#define C_P2 512
#define C_HT 1024
#define C_D1 1536
#define C_D2 1581
#define C_PAD 1626

typedef __attribute__((ext_vector_type(8))) short bf16x8;
typedef __attribute__((ext_vector_type(4))) float f32x4;

__device__ inline ushort f2bf(float x) {
    __hip_bfloat16 b = __float2bfloat16(x);
    return *reinterpret_cast<ushort*>(&b);
}
__device__ inline float bf2f(ushort u) {
    __hip_bfloat16 b;
    *reinterpret_cast<ushort*>(&b) = u;
    return __bfloat162float(b);
}

// ================= k_prep =================
// blocks [0,45):     Y1,Y2 (45x512), Ew[t]
// blocks [45,109):   A_hi/A_lo = bf16-split of h*wpos  (64 blocks x 16 rows)
// blocks [109,205):  B_hi/B_lo rows 0..1535 = bf16-split of W1h|W2h|Wg (96 x 16)
// blocks [205,213):  zero B rows 1536..1663; blk 205 also fills bias_ext base/pad
__global__ __launch_bounds__(256) void k_prep(
    const float* __restrict__ h, const unsigned char* __restrict__ mask,
    const float* __restrict__ emb,
    const float* __restrict__ W1, const float* __restrict__ W2,
    const float* __restrict__ Wg,
    const float* __restrict__ b1, const float* __restrict__ b2,
    const float* __restrict__ bg,
    ushort* __restrict__ A_hi, ushort* __restrict__ A_lo,
    ushort* __restrict__ B_hi, ushort* __restrict__ B_lo,
    float* __restrict__ Y1, float* __restrict__ Y2, float* __restrict__ Ew,
    float* __restrict__ bias_ext) {
    int bid = blockIdx.x;
    int tid = threadIdx.x;

    if (bid < DEPN) {
        int t = bid;
        __shared__ float es[DEPD];
        __shared__ float red[4];
        if (tid < DEPD) es[tid] = emb[t * DEPD + tid];
        __syncthreads();
        float p = 0.f;
        for (int half = 0; half < 2; half++) {
            int o = tid + half * 256;
            float y1 = 0.f, y2 = 0.f;
#pragma unroll
            for (int e = 0; e < DEPD; e++) {
                y1 += es[e] * W1[o * WCOLS + IND + e];
                y2 += es[e] * W2[o * WCOLS + IND + e];
            }
            Y1[t * 512 + o] = y1;
            Y2[t * 512 + o] = y2;
            p += y1 * y2;
        }
        for (int off = 32; off; off >>= 1) p += __shfl_down(p, off, 64);
        if ((tid & 63) == 0) red[tid >> 6] = p;
        __syncthreads();
        if (tid == 0) Ew[t] = red[0] + red[1] + red[2] + red[3];
    } else if (bid < 109) {
        // ---- A conversion: 16 rows, with position-aware weight ----
        int blk = bid - 45;
        int rb = blk * 16;
        int b = rb >> 7;
        __shared__ int sflag, smin, smax;
        __shared__ float w16[16];
        if (tid == 0) { sflag = 0; smin = NL; smax = -1; }
        __syncthreads();
        const int* mi = (const int*)mask;
        if (tid < 128) {
            int v0 = mi[tid], v1 = mi[tid + 128];
            if ((unsigned)v0 > 1u || (unsigned)v1 > 1u) atomicOr(&sflag, 1);
        }
        __syncthreads();
        if (tid < 128) {
            int mval = sflag ? (int)mask[b * NL + tid] : mi[b * NL + tid];
            if (mval) { atomicMin(&smin, tid); atomicMax(&smax, tid); }
        }
        __syncthreads();
        if (tid < 16) {
            int any = (smax >= 0);
            int s = any ? smin : 0;
            int e = any ? smax : (NL - 1);
            int i = (rb & 127) + tid;
            const float invL = 1.0f / (float)NL;
            float w;
            if (i < s)      w = 1.0f - (float)(s - i) * invL;
            else if (i > e) w = 1.0f - (float)(i - e) * invL;
            else            w = 0.0f;
            int mval = sflag ? (int)mask[b * NL + i] : mi[b * NL + i];
            if (mval) w = 0.0f;
            w16[tid] = w;
        }
        __syncthreads();
        for (int idx = tid; idx < 16 * 128; idx += 256) {
            int r = idx >> 7, dc = (idx & 127) << 2;
            float4 hv = *(const float4*)&h[(size_t)(rb + r) * IND + dc];
            float wv = w16[r];
            hv.x *= wv; hv.y *= wv; hv.z *= wv; hv.w *= wv;
            ushort4 hi4;
            hi4.x = f2bf(hv.x); hi4.y = f2bf(hv.y); hi4.z = f2bf(hv.z); hi4.w = f2bf(hv.w);
            ushort4 lo4;
            lo4.x = f2bf(hv.x - bf2f(hi4.x));
            lo4.y = f2bf(hv.y - bf2f(hi4.y));
            lo4.z = f2bf(hv.z - bf2f(hi4.z));
            lo4.w = f2bf(hv.w - bf2f(hi4.w));
            *(ushort4*)&A_hi[(size_t)(rb + r) * IND + dc] = hi4;
            *(ushort4*)&A_lo[(size_t)(rb + r) * IND + dc] = lo4;
        }
    } else if (bid < 205) {
        // ---- B conversion rows 0..1535 ----
        int blk = bid - 109;
        int nb = blk * 16;
        for (int idx = tid; idx < 16 * 128; idx += 256) {
            int r = idx >> 7, dc = (idx & 127) << 2;
            int n = nb + r;
            const float* src;
            if (n < 512)       src = W1 + (size_t)n * WCOLS + dc;
            else if (n < 1024) src = W2 + (size_t)(n - 512) * WCOLS + dc;
            else               src = Wg + (size_t)(n - 1024) * IND + dc;
            float4 wv = *(const float4*)src;
            ushort4 hi4;
            hi4.x = f2bf(wv.x); hi4.y = f2bf(wv.y); hi4.z = f2bf(wv.z); hi4.w = f2bf(wv.w);
            ushort4 lo4;
            lo4.x = f2bf(wv.x - bf2f(hi4.x));
            lo4.y = f2bf(wv.y - bf2f(hi4.y));
            lo4.z = f2bf(wv.z - bf2f(hi4.z));
            lo4.w = f2bf(wv.w - bf2f(hi4.w));
            *(ushort4*)&B_hi[(size_t)n * IND + dc] = hi4;
            *(ushort4*)&B_lo[(size_t)n * IND + dc] = lo4;
        }
    } else {
        // ---- zero B rows 1536..1663; blk 205: bias_ext base+pad ----
        int blk = bid - 205;             // 0..7
        int nb = 1536 + blk * 16;
        ushort4 z4 = {0, 0, 0, 0};
        for (int idx = tid; idx < 16 * 128; idx += 256) {
            int r = idx >> 7, dc = (idx & 127) << 2;
            int n = nb + r;
            *(ushort4*)&B_hi[(size_t)n * IND + dc] = z4;
            *(ushort4*)&B_lo[(size_t)n * IND + dc] = z4;
        }
        if (blk == 0) {
            for (int i = tid; i < 512; i += 256) {
                bias_ext[C_P1 + i] = b1[i];
                bias_ext[C_P2 + i] = b2[i];
                bias_ext[C_HT + i] = bg[i];
            }
            if (tid < NP - C_PAD) bias_ext[C_PAD + tid] = 0.f;
        }
    }
}

// ================= k_prep2: Z rows of B + D-bias =================
// grid (45 t, 2 m, 4 dq), 256 thr.  Thread half owns 256 o's for
// d = dq*128 + (tid&127); halves combined via LDS.
__global__ __launch_bounds__(256) void k_prep2(
    const float* __restrict__ W1, const float* __restrict__ W2,
    const float* __restrict__ b1, const float* __restrict__ b2,
    const float* __restrict__ Y1, const float* __restrict__ Y2,
    const float* __restrict__ Ew,
    ushort* __restrict__ B_hi, ushort* __restrict__ B_lo,
    float* __restrict__ bias_ext) {
    int t = blockIdx.x;
    int m = blockIdx.y;
    int dq = blockIdx.z;
    int tid = threadIdx.x;
    int dloc = tid & 127, half = tid >> 7;
    __shared__ float ys[512];
    __shared__ float part[256];
    const float* Y = (m == 0) ? Y2 : Y1;
    ys[tid] = Y[t * 512 + tid];
    ys[tid + 256] = Y[t * 512 + tid + 256];
    __syncthreads();

    const float* Wsrc = (m == 0) ? W1 : W2;
    int d = dq * 128 + dloc;
    int obase = half * 256;
    float s = 0.f;
#pragma unroll 16
    for (int oo = 0; oo < 256; oo++)
        s += Wsrc[(size_t)(obase + oo) * WCOLS + d] * ys[obase + oo];
    part[tid] = s;
    __syncthreads();

    int row = ((m == 0) ? C_D1 : C_D2) + t;
    if (half == 0) {
        float tot = part[dloc] + part[128 + dloc];
        ushort hi = f2bf(tot);
        ushort lo = f2bf(tot - bf2f(hi));
        B_hi[(size_t)row * IND + d] = hi;
        B_lo[(size_t)row * IND + d] = lo;
    }

    if (dq == 0 && tid < 64) {
        const float* bb = (m == 0) ? b1 : b2;
        float sb = 0.f;
#pragma unroll
        for (int k = 0; k < 8; k++) sb += bb[tid + k * 64] * ys[tid + k * 64];
        for (int off = 32; off; off >>= 1) sb += __shfl_down(sb, off, 64);
        if (tid == 0) bias_ext[row] = sb + ((m == 0) ? Ew[t] : 0.f);
    }
}

// ================= k3: Pout = A @ B^T + bias_ext  (MFMA, hi/lo bf16) =================
// 128 thr = 2 waves; wave tile 32x32 (2m x 2n frags of 16x16x32); block
// tile 64m x 32n; grid (16, 52) = 832 blocks -> 3.25 waves/SIMD.
// 2-deep register pipeline; combined lookahead ~= L2 latency.
#define LOADSET(P, KS) \
    P##a0h = *(const bf16x8*)(A_hi + (size_t)rA0 * IND + (KS) * 32 + kg8); \
    P##a0l = *(const bf16x8*)(A_lo + (size_t)rA0 * IND + (KS) * 32 + kg8); \
    P##a1h = *(const bf16x8*)(A_hi + (size_t)rA1 * IND + (KS) * 32 + kg8); \
    P##a1l = *(const bf16x8*)(A_lo + (size_t)rA1 * IND + (KS) * 32 + kg8); \
    P##b0h = *(const bf16x8*)(B_hi + (size_t)cB0 * IND + (KS) * 32 + kg8); \
    P##b0l = *(const bf16x8*)(B_lo + (size_t)cB0 * IND + (KS) * 32 + kg8); \
    P##b1h = *(const bf16x8*)(B_hi + (size_t)cB1 * IND + (KS) * 32 + kg8); \
    P##b1l = *(const bf16x8*)(B_lo + (size_t)cB1 * IND + (KS) * 32 + kg8);

#define MFMASET(P) \
    acc00 = __builtin_amdgcn_mfma_f32_16x16x32_bf16(P##a0h, P##b0h, acc00, 0, 0, 0); \
    acc00 = __builtin_amdgcn_mfma_f32_16x16x32_bf16(P##a0h, P##b0l, acc00, 0, 0, 0); \
    acc00 = __builtin_amdgcn_mfma_f32_16x16x32_bf16(P##a0l, P##b0h, acc00, 0, 0, 0); \
    acc01 = __builtin_amdgcn_mfma_f32_16x16x32_bf16(P##a0h, P##b1h, acc01, 0, 0, 0); \
    acc01 = __builtin_amdgcn_mfma_f32_16x16x32_bf16(P##a0h, P##b1l, acc01, 0, 0, 0); \
    acc01 = __builtin_amdgcn_mfma_f32_16x16x32_bf16(P##a0l, P##b1h, acc01, 0, 0, 0); \
    acc10 = __builtin_amdgcn_mfma_f32_16x16x32_bf16(P##a1h, P##b0h, acc10, 0, 0, 0); \
    acc10 = __builtin_amdgcn_mfma_f32_16x16x32_bf16(P##a1h, P##b0l, acc10, 0, 0, 0); \
    acc10 = __builtin_amdgcn_mfma_f32_16x16x32_bf16(P##a1l, P##b0h, acc10, 0, 0, 0); \
    acc11 = __builtin_amdgcn_mfma_f32_16x16x32_bf16(P##a1h, P##b1h, acc11, 0, 0, 0); \
    acc11 = __builtin_amdgcn_mfma_f32_16x16x32_bf16(P##a1h, P##b1l, acc11, 0, 0, 0); \
    acc11 = __builtin_amdgcn_mfma_f32_16x16x32_bf16(P##a1l, P##b1h, acc11, 0, 0, 0);

__global__ __launch_bounds__(128) void k3_gemm(
    const ushort* __restrict__ A_hi, const ushort* __restrict__ A_lo,
    const ushort* __restrict__ B_hi, const ushort* __restrict__ B_lo,
    const float* __restrict__ bias_ext, float* __restrict__ Pout) {
    int tid = threadIdx.x;
    int wid = tid >> 6, lane = tid & 63;
    int lrow = lane & 15, kg8 = (lane >> 4) << 3;
    int mbase = blockIdx.x * 64 + wid * 32;
    int nbase = blockIdx.y * 32;
    int rA0 = mbase + lrow, rA1 = rA0 + 16;
    int cB0 = nbase + lrow, cB1 = cB0 + 16;

    f32x4 acc00 = {0.f, 0.f, 0.f, 0.f};
    f32x4 acc01 = acc00, acc10 = acc00, acc11 = acc00;
    bf16x8 pa0h, pa0l, pa1h, pa1l, pb0h, pb0l, pb1h, pb1l;
    bf16x8 qa0h, qa0l, qa1h, qa1l, qb0h, qb0l, qb1h, qb1l;

    LOADSET(p, 0)
#pragma unroll
    for (int ks = 0; ks < 16; ks += 2) {
        LOADSET(q, ks + 1)
        MFMASET(p)
        int kn = (ks + 2) & 15;      // last iter: dummy reload of 0 (unused)
        LOADSET(p, kn)
        MFMASET(q)
    }

    int r0 = (lane >> 4) << 2;
    int col0 = nbase + lrow;
    int col1 = col0 + 16;
    float bv0 = bias_ext[col0];
    float bv1 = bias_ext[col1];
#pragma unroll
    for (int r = 0; r < 4; ++r) {
        int row0 = mbase + r0 + r;
        int row1 = row0 + 16;
        Pout[(size_t)row0 * NP + col0] = acc00[r] + bv0;
        Pout[(size_t)row0 * NP + col1] = acc01[r] + bv1;
        Pout[(size_t)row1 * NP + col0] = acc10[r] + bv0;
        Pout[(size_t)row1 * NP + col1] = acc11[r] + bv1;
    }
}

// ================= k5: scores lookup + normalize + A@HT + relu =================
__global__ __launch_bounds__(128) void k5_out(
    const float* __restrict__ P, const int* __restrict__ dep,
    const float* __restrict__ bias, float* __restrict__ out) {
    int row = blockIdx.x;        // 1024
    int b = row >> 7;
    int tid = threadIdx.x;       // 128
    __shared__ float comb[DEPN];
    __shared__ float a[NL];
    __shared__ float red[2];
    __shared__ float sumv;

    const float* Prow = P + (size_t)row * NP;
    float4 p1 = *(const float4*)(Prow + C_P1 + tid * 4);
    float4 p2 = *(const float4*)(Prow + C_P2 + tid * 4);
    float lc = p1.x * p2.x + p1.y * p2.y + p1.z * p2.z + p1.w * p2.w;
    for (int off = 32; off; off >>= 1) lc += __shfl_down(lc, off, 64);
    if ((tid & 63) == 0) red[tid >> 6] = lc;
    if (tid < DEPN) comb[tid] = Prow[C_D1 + tid] + Prow[C_D2 + tid];
    __syncthreads();

    float c0 = red[0] + red[1];
    int tt = dep[(size_t)row * NL + tid];
    float sc = (tt != 0) ? expf(c0 + comb[tt]) : 0.f;
    a[tid] = sc;
    __syncthreads();
    if (tid < 64) {
        float v = a[tid] + a[tid + 64];
        for (int off = 32; off; off >>= 1) v += __shfl_down(v, off, 64);
        if (tid == 0) sumv = v;
    }
    __syncthreads();
    float inv = 1.0f / (sumv + 1e-6f);

    const float* htb = P + (size_t)b * NL * NP + C_HT + tid * 4;
    float sx = 0.f, sy = 0.f, sz = 0.f, sw = 0.f;
#pragma unroll 8
    for (int j = 0; j < NL; j += 2) {
        float a0 = a[j], a1 = a[j + 1];
        float4 v0 = *(const float4*)(htb + (size_t)j * NP);
        float4 v1 = *(const float4*)(htb + (size_t)(j + 1) * NP);
        sx += a0 * v0.x + a1 * v1.x;
        sy += a0 * v0.y + a1 * v1.y;
        sz += a0 * v0.z + a1 * v1.z;
        sw += a0 * v0.w + a1 * v1.w;
    }
    float4 bv = *(const float4*)&bias[tid * 4];
    float4 o;
    o.x = fmaxf(sx * inv + bv.x, 0.f);
    o.y = fmaxf(sy * inv + bv.y, 0.f);
    o.z = fmaxf(sz * inv + bv.z, 0.f);
    o.w = fmaxf(sw * inv + bv.w, 0.f);
    *(float4*)&out[(size_t)row * 512 + tid * 4] = o;
}

extern "C" void kernel_launch(void* const* d_in, const int* in_sizes, int n_in,
                              void* d_out, int out_size, void* d_ws, size_t ws_size,
                              hipStream_t stream) {
    const float* h    = (const float*)d_in[0];
    const int* dep    = (const int*)d_in[1];
    const unsigned char* mask = (const unsigned char*)d_in[2];
    const float* emb  = (const float*)d_in[3];
    const float* W1   = (const float*)d_in[4];
    const float* b1   = (const float*)d_in[5];
    const float* W2   = (const float*)d_in[6];
    const float* b2   = (const float*)d_in[7];
    const float* Wg   = (const float*)d_in[8];
    const float* bg   = (const float*)d_in[9];
    const float* bias = (const float*)d_in[10];
    float* out = (float*)d_out;

    char* p = (char*)d_ws;
    ushort* A_hi = (ushort*)p;  p += (size_t)1024 * 512 * 2;   // 1 MB
    ushort* A_lo = (ushort*)p;  p += (size_t)1024 * 512 * 2;
    ushort* B_hi = (ushort*)p;  p += (size_t)1664 * 512 * 2;   // 1.7 MB
    ushort* B_lo = (ushort*)p;  p += (size_t)1664 * 512 * 2;
    float* bias_ext = (float*)p; p += 1664 * 4;
    float* Y1 = (float*)p;      p += 23040 * 4;
    float* Y2 = (float*)p;      p += 23040 * 4;
    float* Ew = (float*)p;      p += 64 * 4;
    float* Pout = (float*)p;    // 1024*1664*4 = 6.8 MB

    k_prep<<<213, 256, 0, stream>>>(h, mask, emb, W1, W2, Wg, b1, b2, bg,
                                    A_hi, A_lo, B_hi, B_lo, Y1, Y2, Ew, bias_ext);
    dim3 g2(DEPN, 2, 4);
    k_prep2<<<g2, 256, 0, stream>>>(W1, W2, b1, b2, Y1, Y2, Ew, B_hi, B_lo, bias_ext);
    dim3 g3(16, 52);
    k3_gemm<<<g3, 128, 0, stream>>>(A_hi, A_lo, B_hi, B_lo, bias_ext, Pout);
    k5_out<<<NBATCH * NL, 128, 0, stream>>>(Pout, dep, bias, out);
}